// Round 8
// baseline (692.091 us; speedup 1.0000x reference)
//
#include <hip/hip_runtime.h>

#define NN 50000
#define MP 50048   // 391 * 128
#define DD 512
#define EE 800000
#define NSCAN 196  // ceil(NN/256)
#define SCB 3321   // ceil((EE+NN)/256) scatter blocks fused into gemm1
#define G1TILES 1564  // (MP/128)*(512/128)

typedef unsigned short u16;
typedef __attribute__((ext_vector_type(4))) float f32x4;
typedef __attribute__((ext_vector_type(8))) __bf16 bf16x8;
typedef __attribute__((ext_vector_type(8))) short s16x8;
typedef __attribute__((ext_vector_type(4))) short s16x4;

typedef __attribute__((address_space(1))) const void GVoid;
typedef __attribute__((address_space(3))) void LVoid;

__device__ __forceinline__ u16 f2bf(float f) {
  union { float f; unsigned u; } x; x.f = f;
  unsigned r = x.u + 0x7fffu + ((x.u >> 16) & 1u);   // RTNE
  return (u16)(r >> 16);
}
__device__ __forceinline__ float bf2f(u16 b) {
  union { unsigned u; float f; } x; x.u = ((unsigned)b) << 16;
  return x.f;
}

// ---------------- setup: cnt=1 (self-loop) + all 3 weight transposes, one launch ----------------

__global__ __launch_bounds__(256) void setup_k(int* __restrict__ cnt,
                                               const float* __restrict__ W1, u16* __restrict__ W1T,
                                               const float* __restrict__ W2, u16* __restrict__ W2T,
                                               const float* __restrict__ Wo, u16* __restrict__ WoT) {
  const int b = (int)blockIdx.x, t = threadIdx.x;
  if (b < 196) { int i = b * 256 + t; if (i < NN) cnt[i] = 1; return; }
  const float* W; u16* WT; int ncols, idx;
  if (b < 1220)      { W = W1; WT = W1T; ncols = 512; idx = (b - 196) * 256 + t; }
  else if (b < 2244) { W = W2; WT = W2T; ncols = 512; idx = (b - 1220) * 256 + t; }
  else               { W = Wo; WT = WoT; ncols = 256; idx = (b - 2244) * 256 + t; }
  if (idx >= 512 * ncols) return;
  int n = idx >> 9, k = idx & 511;             // WT[ncols][512] = W^T
  WT[idx] = f2bf(W[(size_t)k * ncols + n]);
}

__global__ __launch_bounds__(256) void count_k(const int* __restrict__ dst, int* __restrict__ cnt) {
  int e = blockIdx.x * 256 + threadIdx.x;
  if (e < EE) atomicAdd(&cnt[dst[e]], 1);
}

// --- 3-stage parallel exclusive scan over cnt[NN]; scan3 also emits dinv ---

__global__ __launch_bounds__(256) void scan1_k(const int* __restrict__ cnt, int* __restrict__ bsum) {
  __shared__ int s[256];
  const int t = threadIdx.x;
  const int i = blockIdx.x * 256 + t;
  s[t] = (i < NN) ? cnt[i] : 0;
  __syncthreads();
  for (int off = 128; off > 0; off >>= 1) {
    if (t < off) s[t] += s[t + off];
    __syncthreads();
  }
  if (t == 0) bsum[blockIdx.x] = s[0];
}

__global__ __launch_bounds__(256) void scan2_k(const int* __restrict__ bsum, int* __restrict__ boff) {
  __shared__ int s[256];
  const int t = threadIdx.x;
  const int v = (t < NSCAN) ? bsum[t] : 0;
  s[t] = v;
  __syncthreads();
  for (int off = 1; off < 256; off <<= 1) {    // inclusive Hillis-Steele
    int a = s[t];
    int b = (t >= off) ? s[t - off] : 0;
    __syncthreads();
    s[t] = a + b;
    __syncthreads();
  }
  if (t < NSCAN) boff[t] = s[t] - v;           // exclusive
}

__global__ __launch_bounds__(256) void scan3_k(const int* __restrict__ cnt, const int* __restrict__ boff,
                                               int* __restrict__ rowp, int* __restrict__ cursor,
                                               float* __restrict__ dinv) {
  __shared__ int s[256];
  const int t = threadIdx.x;
  const int i = blockIdx.x * 256 + t;
  const int v = (i < NN) ? cnt[i] : 0;
  s[t] = v;
  __syncthreads();
  for (int off = 1; off < 256; off <<= 1) {    // inclusive
    int a = s[t];
    int b = (t >= off) ? s[t - off] : 0;
    __syncthreads();
    s[t] = a + b;
    __syncthreads();
  }
  const int excl = s[t] - v + boff[blockIdx.x];
  if (i < NN) {
    rowp[i] = excl; cursor[i] = excl;
    dinv[i] = rsqrtf((float)v);                // v includes self-loop
  }
  if (i == NN - 1) rowp[NN] = excl + v;        // total = EE + NN
}

// ---------------- GEMM-1 (f32 A direct, reg-staged) + fused scatter blocks ----------------

__global__ __launch_bounds__(256) void gemm1_k(const float* __restrict__ X, const u16* __restrict__ BT,
                                               u16* __restrict__ C,
                                               const int* __restrict__ src, const int* __restrict__ dst,
                                               const float* __restrict__ dinv, int* __restrict__ cursor,
                                               int2* __restrict__ csr) {
  __shared__ u16 As[2][128 * 32];
  __shared__ u16 Bs[2][128 * 32];
  const int t = threadIdx.x;

  if (blockIdx.x < SCB) {                      // ---- scatter branch ----
    int e = (int)blockIdx.x * 256 + t;
    if (e < EE) {
      int d = dst[e], sn = src[e];
      int pos = atomicAdd(&cursor[d], 1);
      csr[pos] = make_int2(sn, __float_as_int(dinv[sn] * dinv[d]));
    } else if (e < EE + NN) {
      int i = e - EE;                          // self-loop edge
      int pos = atomicAdd(&cursor[i], 1);
      float di = dinv[i];
      csr[pos] = make_int2(i, __float_as_int(di * di));
    }
    return;
  }

  // ---- GEMM branch: bijective XCD chunking over G1TILES ----
  const int g = (int)blockIdx.x - SCB;
  const int xcd = g & 7;
  const int idx = g >> 3;
  const int q = G1TILES >> 3, r = G1TILES & 7;
  const int tile = (xcd < r ? xcd * (q + 1) : r * (q + 1) + (xcd - r) * q) + idx;
  const int bm = tile >> 2;                    // ntn = 4
  const int bn = tile & 3;

  const int lane = t & 63;
  const int wc = (t >> 6) & 1;
  const int wr = (t >> 7) & 1;
  f32x4 acc[4][4] = {};
  const int r0 = t >> 2;                        // staging row 0..63
  const int kc = (t & 3) * 8;                   // staging k-col (elements)
  const int row1 = bm * 128 + 64 + r0;          // only the +64 region can exceed NN
  const float* Xp0 = X + (size_t)(bm * 128 + r0) * DD + kc;
  const float* Xp1 = X + (size_t)(row1 < NN ? row1 : NN - 1) * DD + kc;
  const u16* Bb = BT + (size_t)bn * 128 * DD + (size_t)r0 * DD + kc;

  f32x4 a0, a1, a2, a3;
  auto loadA = [&](int kt) {
    a0 = *(const f32x4*)(Xp0 + kt);
    a1 = *(const f32x4*)(Xp0 + kt + 4);
    a2 = *(const f32x4*)(Xp1 + kt);
    a3 = *(const f32x4*)(Xp1 + kt + 4);
  };
  auto writeA = [&](int buf) {
    bf16x8 w0, w1;
    #pragma unroll
    for (int j = 0; j < 4; ++j) {
      w0[j] = (__bf16)a0[j]; w0[4 + j] = (__bf16)a1[j];
      w1[j] = (__bf16)a2[j]; w1[4 + j] = (__bf16)a3[j];
    }
    *(bf16x8*)&As[buf][t * 8] = w0;
    *(bf16x8*)&As[buf][2048 + t * 8] = w1;
  };
  auto stageB = [&](int buf, int kt) {
    __builtin_amdgcn_global_load_lds((GVoid*)(Bb + kt),           (LVoid*)(&Bs[buf][t * 8]),        16, 0, 0);
    __builtin_amdgcn_global_load_lds((GVoid*)(Bb + 64 * DD + kt), (LVoid*)(&Bs[buf][2048 + t * 8]), 16, 0, 0);
  };

  loadA(0);
  stageB(0, 0);
  writeA(0);
  __syncthreads();                              // buf0 ready (A written, B drained)

  #pragma unroll 2
  for (int step = 0; step < 16; ++step) {
    const int cur = step & 1;
    if (step < 15) { loadA((step + 1) * 32); stageB(cur ^ 1, (step + 1) * 32); }
    bf16x8 af[4], bv[4];
    #pragma unroll
    for (int m = 0; m < 4; ++m)
      af[m] = *(const bf16x8*)&As[cur][(wr * 64 + m * 16 + (lane & 15)) * 32 + (lane >> 4) * 8];
    #pragma unroll
    for (int n = 0; n < 4; ++n)
      bv[n] = *(const bf16x8*)&Bs[cur][(wc * 64 + n * 16 + (lane & 15)) * 32 + (lane >> 4) * 8];
    #pragma unroll
    for (int m = 0; m < 4; ++m) {
      #pragma unroll
      for (int n = 0; n < 4; ++n)
        acc[m][n] = __builtin_amdgcn_mfma_f32_16x16x32_bf16(af[m], bv[n], acc[m][n], 0, 0, 0);
    }
    if (step < 15) writeA(cur ^ 1);             // cvt + ds_write after MFMA (loads in flight during MFMA)
    __syncthreads();
  }

  const int rb = bm * 128 + wr * 64 + ((lane >> 4) * 4);
  const int cb = bn * 128 + wc * 64 + (lane & 15);
  #pragma unroll
  for (int m = 0; m < 4; ++m) {
    #pragma unroll
    for (int rr = 0; rr < 4; ++rr) {
      const int row = rb + m * 16 + rr;
      if (row < NN) {
        #pragma unroll
        for (int n = 0; n < 4; ++n)
          C[(size_t)row * 512 + cb + n * 16] = f2bf(acc[m][n][rr]);
      }
    }
  }
}

// ---------------- bf16 MFMA GEMM: m97 structure + 2-phase double buffer (layers 2,3) ----------------

template<int OUT_BF16>
__global__ __launch_bounds__(256) void gemm_k(const u16* __restrict__ A, const u16* __restrict__ BT,
                                              void* __restrict__ Cv, const float* __restrict__ bias,
                                              int M, int N) {
  const int nwg = (int)gridDim.x;
  const int id = (int)blockIdx.x;
  const int xcd = id & 7;
  const int idx = id >> 3;
  const int q = nwg >> 3, r = nwg & 7;
  const int tile = (xcd < r ? xcd * (q + 1) : r * (q + 1) + (xcd - r) * q) + idx;
  const int ntn = N >> 7;
  const int bm = tile / ntn;
  const int bn = tile % ntn;

  __shared__ u16 As[2][128 * 32];
  __shared__ u16 Bs[2][128 * 32];
  const int t = threadIdx.x;
  const int lane = t & 63;
  const int wc = (t >> 6) & 1;
  const int wr = (t >> 7) & 1;
  f32x4 acc[4][4] = {};
  const int r0 = t >> 2;
  const int kc = (t & 3) * 8;
  const u16* Ab = A + (size_t)bm * 128 * DD + (size_t)r0 * DD + kc;
  const u16* Bb = BT + (size_t)bn * 128 * DD + (size_t)r0 * DD + kc;

  auto stage = [&](int buf, int kt) {
    __builtin_amdgcn_global_load_lds((GVoid*)(Ab + kt),           (LVoid*)(&As[buf][t * 8]),        16, 0, 0);
    __builtin_amdgcn_global_load_lds((GVoid*)(Ab + 64 * DD + kt), (LVoid*)(&As[buf][2048 + t * 8]), 16, 0, 0);
    __builtin_amdgcn_global_load_lds((GVoid*)(Bb + kt),           (LVoid*)(&Bs[buf][t * 8]),        16, 0, 0);
    __builtin_amdgcn_global_load_lds((GVoid*)(Bb + 64 * DD + kt), (LVoid*)(&Bs[buf][2048 + t * 8]), 16, 0, 0);
  };

  stage(0, 0);
  __syncthreads();

  #pragma unroll 2
  for (int step = 0; step < 16; ++step) {
    const int cur = step & 1;
    if (step < 15) stage(cur ^ 1, (step + 1) * 32);
    bf16x8 af[4], bv[4];
    #pragma unroll
    for (int m = 0; m < 4; ++m)
      af[m] = *(const bf16x8*)&As[cur][(wr * 64 + m * 16 + (lane & 15)) * 32 + (lane >> 4) * 8];
    #pragma unroll
    for (int n = 0; n < 4; ++n)
      bv[n] = *(const bf16x8*)&Bs[cur][(wc * 64 + n * 16 + (lane & 15)) * 32 + (lane >> 4) * 8];
    #pragma unroll
    for (int m = 0; m < 4; ++m) {
      #pragma unroll
      for (int n = 0; n < 4; ++n)
        acc[m][n] = __builtin_amdgcn_mfma_f32_16x16x32_bf16(af[m], bv[n], acc[m][n], 0, 0, 0);
    }
    __syncthreads();
  }

  const int rb = bm * 128 + wr * 64 + ((lane >> 4) * 4);
  const int cb = bn * 128 + wc * 64 + (lane & 15);
  #pragma unroll
  for (int m = 0; m < 4; ++m) {
    #pragma unroll
    for (int rr = 0; rr < 4; ++rr) {
      const int row = rb + m * 16 + rr;
      if (row < M) {
        #pragma unroll
        for (int n = 0; n < 4; ++n) {
          const int col = cb + n * 16;
          float v = acc[m][n][rr];
          if (bias) v += bias[col];
          if (OUT_BF16) ((u16*)Cv)[(size_t)row * N + col] = f2bf(v);
          else          ((float*)Cv)[(size_t)row * N + col] = v;
        }
      }
    }
  }
}

// ---------------- CSR aggregation: XCD-pinned 64-dim slices, 4 edges per wave-step ----------------
// Per-XCD L2 fill port ~460 GB/s is the wall (R6/R7: 0.46 TB/s/XCD at both 8 and 4 XCDs).
// Slice working set 6.4 MB/XCD -> 74% L2 hit (R4-measured), fill ~28+6 MB/XCD -> ~74us floor.
// R4's issue-bound failure fixed by packing 4 edges/wave-instr: lane = (edge-group g=lane>>4)
// x (16 dim-lanes x bf16x4). One load instr = 4 x 128B gathers. Epilogue: shfl_xor(16,32)
// folds the 4 edge-groups; group 0 writes 128B.

__global__ __launch_bounds__(256) void aggregate_k(const u16* __restrict__ H, const int* __restrict__ rowp,
                                                   const int2* __restrict__ csr,
                                                   const float* __restrict__ bias,
                                                   u16* __restrict__ out) {
  const int slice = (int)blockIdx.x & 7;        // XCD-pinned dim slice
  const int grp = (int)blockIdx.x >> 3;         // node group 0..12499
  const int wid = threadIdx.x >> 6;
  const int lane = threadIdx.x & 63;
  const int g = lane >> 4;                      // edge sub-group 0..3
  const int l = lane & 15;                      // dim sub-lane
  const int node = grp * 4 + wid;
  const int d0 = slice * 64 + l * 4;
  const int beg = rowp[node];
  const int end = rowp[node + 1];
  const u16* Hd = H + d0;
  float a0 = 0.f, a1 = 0.f, a2 = 0.f, a3 = 0.f;
  for (int e = beg + g; ; e += 4) {
    // uniform trip count per group pair via predicated tail (w=0, src=node: always valid row)
    if (__builtin_amdgcn_ballot_w64(e < end) == 0ull) break;
    const bool ok = e < end;
    const int2 c = ok ? csr[e] : make_int2(node, 0);
    const float w = __int_as_float(c.y);
    const s16x4 v = *(const s16x4*)(Hd + (size_t)c.x * DD);
    a0 += bf2f((u16)v[0]) * w;
    a1 += bf2f((u16)v[1]) * w;
    a2 += bf2f((u16)v[2]) * w;
    a3 += bf2f((u16)v[3]) * w;
  }
  // fold edge-groups: lanes differing only in bits 4,5 hold partial sums of the same dims
  a0 += __shfl_xor(a0, 16); a0 += __shfl_xor(a0, 32);
  a1 += __shfl_xor(a1, 16); a1 += __shfl_xor(a1, 32);
  a2 += __shfl_xor(a2, 16); a2 += __shfl_xor(a2, 32);
  a3 += __shfl_xor(a3, 16); a3 += __shfl_xor(a3, 32);
  if (g == 0) {
    s16x4 o;
    o[0] = (short)f2bf(fmaxf(a0 + bias[d0 + 0], 0.f));
    o[1] = (short)f2bf(fmaxf(a1 + bias[d0 + 1], 0.f));
    o[2] = (short)f2bf(fmaxf(a2 + bias[d0 + 2], 0.f));
    o[3] = (short)f2bf(fmaxf(a3 + bias[d0 + 3], 0.f));
    *(s16x4*)(out + (size_t)node * DD + d0) = o;
  }
}

// ---------------- launch ----------------

extern "C" void kernel_launch(void* const* d_in, const int* in_sizes, int n_in,
                              void* d_out, int out_size, void* d_ws, size_t ws_size,
                              hipStream_t stream) {
  const float* x    = (const float*)d_in[0];
  const int*   ei   = (const int*)d_in[1];
  const float* W1   = (const float*)d_in[2];
  const float* b1   = (const float*)d_in[3];
  const float* W2   = (const float*)d_in[4];
  const float* b2   = (const float*)d_in[5];
  const float* Wout = (const float*)d_in[6];
  const float* bout = (const float*)d_in[7];
  float* out = (float*)d_out;
  (void)in_sizes; (void)n_in; (void)out_size; (void)ws_size;

  char* ws = (char*)d_ws;
  size_t off = 0;
  auto alloc = [&](size_t bytes) -> char* {
    char* p = ws + off;
    off = (off + bytes + 255) & ~(size_t)255;
    return p;
  };
  u16*   xb   = (u16*)alloc((size_t)MP * DD * 2);   // activations bf16 (pad rows unused-garbage)
  u16*   H    = (u16*)alloc((size_t)NN * DD * 2);   // GEMM output bf16
  u16*   W1T  = (u16*)alloc(512 * 512 * 2);
  u16*   W2T  = (u16*)alloc(512 * 512 * 2);
  u16*   WoT  = (u16*)alloc(256 * 512 * 2);
  int*   cnt  = (int*)alloc(NN * 4);
  float* dinv = (float*)alloc(NN * 4);
  int*   rowp = (int*)alloc((NN + 1) * 4);
  int*   cur  = (int*)alloc(NN * 4);
  int2*  csr  = (int2*)alloc((size_t)(EE + NN) * 8);
  int*   bsum = (int*)alloc(NSCAN * 4);
  int*   boff = (int*)alloc(NSCAN * 4);

  const int* srcp = ei;        // edge_index[0]
  const int* dstp = ei + EE;   // edge_index[1]

  setup_k<<<2756, 256, 0, stream>>>(cnt, W1, W1T, W2, W2T, Wout, WoT);
  count_k<<<(EE + 255) / 256, 256, 0, stream>>>(dstp, cnt);
  scan1_k<<<NSCAN, 256, 0, stream>>>(cnt, bsum);
  scan2_k<<<1, 256, 0, stream>>>(bsum, boff);
  scan3_k<<<NSCAN, 256, 0, stream>>>(cnt, boff, rowp, cur, dinv);

  const int agg_grid = (NN / 4) * 8;            // 12500 node-groups x 8 XCD slices

  // layer 1 (fused scatter): H = bf16(x) @ W1 ; xb = relu(agg(H) + b1)
  gemm1_k<<<SCB + G1TILES, 256, 0, stream>>>(x, W1T, H, srcp, dstp, dinv, cur, csr);
  aggregate_k<<<agg_grid, 256, 0, stream>>>(H, rowp, csr, b1, xb);
  // layer 2
  gemm_k<1><<<(MP / 128) * (512 / 128), 256, 0, stream>>>(xb, W2T, (void*)H, nullptr, NN, 512);
  aggregate_k<<<agg_grid, 256, 0, stream>>>(H, rowp, csr, b2, xb);
  // output layer
  gemm_k<0><<<(MP / 128) * (256 / 128), 256, 0, stream>>>(xb, WoT, (void*)out, bout, NN, 256);
}

// Round 9
// 514.264 us; speedup vs baseline: 1.3458x; 1.3458x over previous
//
#include <hip/hip_runtime.h>

#define NN 50000
#define MP 50048   // 391 * 128
#define DD 512
#define EE 800000
#define NSCAN 196  // ceil(NN/256)
#define SCB 3321   // ceil((EE+NN)/256) scatter blocks fused into gemm1
#define G1TILES 1564  // (MP/128)*(512/128)

typedef unsigned short u16;
typedef __attribute__((ext_vector_type(4))) float f32x4;
typedef __attribute__((ext_vector_type(8))) __bf16 bf16x8;
typedef __attribute__((ext_vector_type(8))) short s16x8;
typedef __attribute__((ext_vector_type(4))) short s16x4;

typedef __attribute__((address_space(1))) const void GVoid;
typedef __attribute__((address_space(3))) void LVoid;

__device__ __forceinline__ u16 f2bf(float f) {
  union { float f; unsigned u; } x; x.f = f;
  unsigned r = x.u + 0x7fffu + ((x.u >> 16) & 1u);   // RTNE
  return (u16)(r >> 16);
}
__device__ __forceinline__ float bf2f(u16 b) {
  union { unsigned u; float f; } x; x.u = ((unsigned)b) << 16;
  return x.f;
}

// ---------------- setup: cnt=1 (self-loop) + all 3 weight transposes, one launch ----------------

__global__ __launch_bounds__(256) void setup_k(int* __restrict__ cnt,
                                               const float* __restrict__ W1, u16* __restrict__ W1T,
                                               const float* __restrict__ W2, u16* __restrict__ W2T,
                                               const float* __restrict__ Wo, u16* __restrict__ WoT) {
  const int b = (int)blockIdx.x, t = threadIdx.x;
  if (b < 196) { int i = b * 256 + t; if (i < NN) cnt[i] = 1; return; }
  const float* W; u16* WT; int ncols, idx;
  if (b < 1220)      { W = W1; WT = W1T; ncols = 512; idx = (b - 196) * 256 + t; }
  else if (b < 2244) { W = W2; WT = W2T; ncols = 512; idx = (b - 1220) * 256 + t; }
  else               { W = Wo; WT = WoT; ncols = 256; idx = (b - 2244) * 256 + t; }
  if (idx >= 512 * ncols) return;
  int n = idx >> 9, k = idx & 511;             // WT[ncols][512] = W^T
  WT[idx] = f2bf(W[(size_t)k * ncols + n]);
}

__global__ __launch_bounds__(256) void count_k(const int* __restrict__ dst, int* __restrict__ cnt) {
  int e = blockIdx.x * 256 + threadIdx.x;
  if (e < EE) atomicAdd(&cnt[dst[e]], 1);
}

// --- 3-stage parallel exclusive scan over cnt[NN]; scan3 also emits dinv ---

__global__ __launch_bounds__(256) void scan1_k(const int* __restrict__ cnt, int* __restrict__ bsum) {
  __shared__ int s[256];
  const int t = threadIdx.x;
  const int i = blockIdx.x * 256 + t;
  s[t] = (i < NN) ? cnt[i] : 0;
  __syncthreads();
  for (int off = 128; off > 0; off >>= 1) {
    if (t < off) s[t] += s[t + off];
    __syncthreads();
  }
  if (t == 0) bsum[blockIdx.x] = s[0];
}

__global__ __launch_bounds__(256) void scan2_k(const int* __restrict__ bsum, int* __restrict__ boff) {
  __shared__ int s[256];
  const int t = threadIdx.x;
  const int v = (t < NSCAN) ? bsum[t] : 0;
  s[t] = v;
  __syncthreads();
  for (int off = 1; off < 256; off <<= 1) {    // inclusive Hillis-Steele
    int a = s[t];
    int b = (t >= off) ? s[t - off] : 0;
    __syncthreads();
    s[t] = a + b;
    __syncthreads();
  }
  if (t < NSCAN) boff[t] = s[t] - v;           // exclusive
}

__global__ __launch_bounds__(256) void scan3_k(const int* __restrict__ cnt, const int* __restrict__ boff,
                                               int* __restrict__ rowp, int* __restrict__ cursor,
                                               float* __restrict__ dinv) {
  __shared__ int s[256];
  const int t = threadIdx.x;
  const int i = blockIdx.x * 256 + t;
  const int v = (i < NN) ? cnt[i] : 0;
  s[t] = v;
  __syncthreads();
  for (int off = 1; off < 256; off <<= 1) {    // inclusive
    int a = s[t];
    int b = (t >= off) ? s[t - off] : 0;
    __syncthreads();
    s[t] = a + b;
    __syncthreads();
  }
  const int excl = s[t] - v + boff[blockIdx.x];
  if (i < NN) {
    rowp[i] = excl; cursor[i] = excl;
    dinv[i] = rsqrtf((float)v);                // v includes self-loop
  }
  if (i == NN - 1) rowp[NN] = excl + v;        // total = EE + NN
}

// ---------------- GEMM-1 (f32 A direct, reg-staged) + fused scatter blocks ----------------

__global__ __launch_bounds__(256) void gemm1_k(const float* __restrict__ X, const u16* __restrict__ BT,
                                               u16* __restrict__ C,
                                               const int* __restrict__ src, const int* __restrict__ dst,
                                               const float* __restrict__ dinv, int* __restrict__ cursor,
                                               int2* __restrict__ csr) {
  __shared__ u16 As[2][128 * 32];
  __shared__ u16 Bs[2][128 * 32];
  const int t = threadIdx.x;

  if (blockIdx.x < SCB) {                      // ---- scatter branch ----
    int e = (int)blockIdx.x * 256 + t;
    if (e < EE) {
      int d = dst[e], sn = src[e];
      int pos = atomicAdd(&cursor[d], 1);
      csr[pos] = make_int2(sn, __float_as_int(dinv[sn] * dinv[d]));
    } else if (e < EE + NN) {
      int i = e - EE;                          // self-loop edge
      int pos = atomicAdd(&cursor[i], 1);
      float di = dinv[i];
      csr[pos] = make_int2(i, __float_as_int(di * di));
    }
    return;
  }

  // ---- GEMM branch: bijective XCD chunking over G1TILES ----
  const int g = (int)blockIdx.x - SCB;
  const int xcd = g & 7;
  const int idx = g >> 3;
  const int q = G1TILES >> 3, r = G1TILES & 7;
  const int tile = (xcd < r ? xcd * (q + 1) : r * (q + 1) + (xcd - r) * q) + idx;
  const int bm = tile >> 2;                    // ntn = 4
  const int bn = tile & 3;

  const int lane = t & 63;
  const int wc = (t >> 6) & 1;
  const int wr = (t >> 7) & 1;
  f32x4 acc[4][4] = {};
  const int r0 = t >> 2;                        // staging row 0..63
  const int kc = (t & 3) * 8;                   // staging k-col (elements)
  const int row1 = bm * 128 + 64 + r0;          // only the +64 region can exceed NN
  const float* Xp0 = X + (size_t)(bm * 128 + r0) * DD + kc;
  const float* Xp1 = X + (size_t)(row1 < NN ? row1 : NN - 1) * DD + kc;
  const u16* Bb = BT + (size_t)bn * 128 * DD + (size_t)r0 * DD + kc;

  f32x4 a0, a1, a2, a3;
  auto loadA = [&](int kt) {
    a0 = *(const f32x4*)(Xp0 + kt);
    a1 = *(const f32x4*)(Xp0 + kt + 4);
    a2 = *(const f32x4*)(Xp1 + kt);
    a3 = *(const f32x4*)(Xp1 + kt + 4);
  };
  auto writeA = [&](int buf) {
    bf16x8 w0, w1;
    #pragma unroll
    for (int j = 0; j < 4; ++j) {
      w0[j] = (__bf16)a0[j]; w0[4 + j] = (__bf16)a1[j];
      w1[j] = (__bf16)a2[j]; w1[4 + j] = (__bf16)a3[j];
    }
    *(bf16x8*)&As[buf][t * 8] = w0;
    *(bf16x8*)&As[buf][2048 + t * 8] = w1;
  };
  auto stageB = [&](int buf, int kt) {
    __builtin_amdgcn_global_load_lds((GVoid*)(Bb + kt),           (LVoid*)(&Bs[buf][t * 8]),        16, 0, 0);
    __builtin_amdgcn_global_load_lds((GVoid*)(Bb + 64 * DD + kt), (LVoid*)(&Bs[buf][2048 + t * 8]), 16, 0, 0);
  };

  loadA(0);
  stageB(0, 0);
  writeA(0);
  __syncthreads();                              // buf0 ready (A written, B drained)

  #pragma unroll 2
  for (int step = 0; step < 16; ++step) {
    const int cur = step & 1;
    if (step < 15) { loadA((step + 1) * 32); stageB(cur ^ 1, (step + 1) * 32); }
    bf16x8 af[4], bv[4];
    #pragma unroll
    for (int m = 0; m < 4; ++m)
      af[m] = *(const bf16x8*)&As[cur][(wr * 64 + m * 16 + (lane & 15)) * 32 + (lane >> 4) * 8];
    #pragma unroll
    for (int n = 0; n < 4; ++n)
      bv[n] = *(const bf16x8*)&Bs[cur][(wc * 64 + n * 16 + (lane & 15)) * 32 + (lane >> 4) * 8];
    #pragma unroll
    for (int m = 0; m < 4; ++m) {
      #pragma unroll
      for (int n = 0; n < 4; ++n)
        acc[m][n] = __builtin_amdgcn_mfma_f32_16x16x32_bf16(af[m], bv[n], acc[m][n], 0, 0, 0);
    }
    if (step < 15) writeA(cur ^ 1);             // cvt + ds_write after MFMA (loads in flight during MFMA)
    __syncthreads();
  }

  const int rb = bm * 128 + wr * 64 + ((lane >> 4) * 4);
  const int cb = bn * 128 + wc * 64 + (lane & 15);
  #pragma unroll
  for (int m = 0; m < 4; ++m) {
    #pragma unroll
    for (int rr = 0; rr < 4; ++rr) {
      const int row = rb + m * 16 + rr;
      if (row < NN) {
        #pragma unroll
        for (int n = 0; n < 4; ++n)
          C[(size_t)row * 512 + cb + n * 16] = f2bf(acc[m][n][rr]);
      }
    }
  }
}

// ---------------- bf16 MFMA GEMM: m97 structure + 2-phase double buffer (layers 2,3) ----------------

template<int OUT_BF16>
__global__ __launch_bounds__(256) void gemm_k(const u16* __restrict__ A, const u16* __restrict__ BT,
                                              void* __restrict__ Cv, const float* __restrict__ bias,
                                              int M, int N) {
  const int nwg = (int)gridDim.x;
  const int id = (int)blockIdx.x;
  const int xcd = id & 7;
  const int idx = id >> 3;
  const int q = nwg >> 3, r = nwg & 7;
  const int tile = (xcd < r ? xcd * (q + 1) : r * (q + 1) + (xcd - r) * q) + idx;
  const int ntn = N >> 7;
  const int bm = tile / ntn;
  const int bn = tile % ntn;

  __shared__ u16 As[2][128 * 32];
  __shared__ u16 Bs[2][128 * 32];
  const int t = threadIdx.x;
  const int lane = t & 63;
  const int wc = (t >> 6) & 1;
  const int wr = (t >> 7) & 1;
  f32x4 acc[4][4] = {};
  const int r0 = t >> 2;
  const int kc = (t & 3) * 8;
  const u16* Ab = A + (size_t)bm * 128 * DD + (size_t)r0 * DD + kc;
  const u16* Bb = BT + (size_t)bn * 128 * DD + (size_t)r0 * DD + kc;

  auto stage = [&](int buf, int kt) {
    __builtin_amdgcn_global_load_lds((GVoid*)(Ab + kt),           (LVoid*)(&As[buf][t * 8]),        16, 0, 0);
    __builtin_amdgcn_global_load_lds((GVoid*)(Ab + 64 * DD + kt), (LVoid*)(&As[buf][2048 + t * 8]), 16, 0, 0);
    __builtin_amdgcn_global_load_lds((GVoid*)(Bb + kt),           (LVoid*)(&Bs[buf][t * 8]),        16, 0, 0);
    __builtin_amdgcn_global_load_lds((GVoid*)(Bb + 64 * DD + kt), (LVoid*)(&Bs[buf][2048 + t * 8]), 16, 0, 0);
  };

  stage(0, 0);
  __syncthreads();

  #pragma unroll 2
  for (int step = 0; step < 16; ++step) {
    const int cur = step & 1;
    if (step < 15) stage(cur ^ 1, (step + 1) * 32);
    bf16x8 af[4], bv[4];
    #pragma unroll
    for (int m = 0; m < 4; ++m)
      af[m] = *(const bf16x8*)&As[cur][(wr * 64 + m * 16 + (lane & 15)) * 32 + (lane >> 4) * 8];
    #pragma unroll
    for (int n = 0; n < 4; ++n)
      bv[n] = *(const bf16x8*)&Bs[cur][(wc * 64 + n * 16 + (lane & 15)) * 32 + (lane >> 4) * 8];
    #pragma unroll
    for (int m = 0; m < 4; ++m) {
      #pragma unroll
      for (int n = 0; n < 4; ++n)
        acc[m][n] = __builtin_amdgcn_mfma_f32_16x16x32_bf16(af[m], bv[n], acc[m][n], 0, 0, 0);
    }
    __syncthreads();
  }

  const int rb = bm * 128 + wr * 64 + ((lane >> 4) * 4);
  const int cb = bn * 128 + wc * 64 + (lane & 15);
  #pragma unroll
  for (int m = 0; m < 4; ++m) {
    #pragma unroll
    for (int rr = 0; rr < 4; ++rr) {
      const int row = rb + m * 16 + rr;
      if (row < M) {
        #pragma unroll
        for (int n = 0; n < 4; ++n) {
          const int col = cb + n * 16;
          float v = acc[m][n][rr];
          if (bias) v += bias[col];
          if (OUT_BF16) ((u16*)Cv)[(size_t)row * N + col] = f2bf(v);
          else          ((float*)Cv)[(size_t)row * N + col] = v;
        }
      }
    }
  }
}

// ---------------- CSR aggregation: XCD-pinned 64-dim slices, batched-MLP ----------------
// R8 was dependence-serialized (csr load -> gather per iter = 1 outstanding gather/wave
// -> 117 GB/s/XCD, 4x under the 460 GB/s/XCD fill port from R6/R7). Fix: one coalesced
// wave-load pulls <=64 csr entries to registers; (src,w) broadcast per round via shfl
// (register traffic); gathers issued 4 rounds deep (16 edges = 2KB in flight) before FMA.
// Invalid tail -> (src=node, w=0): valid row, zero contribution.

__global__ __launch_bounds__(256) void aggregate_k(const u16* __restrict__ H, const int* __restrict__ rowp,
                                                   const int2* __restrict__ csr,
                                                   const float* __restrict__ bias,
                                                   u16* __restrict__ out) {
  const int slice = (int)blockIdx.x & 7;        // XCD-pinned dim slice
  const int grp = (int)blockIdx.x >> 3;         // node group 0..12499
  const int wid = threadIdx.x >> 6;
  const int lane = threadIdx.x & 63;
  const int g = lane >> 4;                      // edge sub-group 0..3
  const int l = lane & 15;                      // dim sub-lane
  const int node = grp * 4 + wid;
  const int d0 = slice * 64 + l * 4;
  const int beg = rowp[node];
  const int end = rowp[node + 1];
  const u16* Hd = H + d0;
  float a0 = 0.f, a1 = 0.f, a2 = 0.f, a3 = 0.f;

  for (int base = beg; base < end; base += 64) {         // one iter for deg<=64 (typical 17)
    const int nch = min(64, end - base);
    const int2 call = (lane < nch) ? csr[base + lane] : make_int2(node, 0);
    const int rounds = (nch + 3) >> 2;
    for (int rr = 0; rr < rounds; rr += 4) {             // 4-deep gather pipeline
      s16x4 v[4];
      float w[4];
      #pragma unroll
      for (int k = 0; k < 4; ++k) {
        const int er = (rr + k) * 4 + g;                 // edge slot within chunk
        const bool ok = (rr + k) < rounds && er < nch;
        const int lsrc = er & 63;
        int sx = __shfl(call.x, lsrc);
        int sy = __shfl(call.y, lsrc);
        sx = ok ? sx : node;
        w[k] = ok ? __int_as_float(sy) : 0.f;
        v[k] = *(const s16x4*)(Hd + (size_t)sx * DD);    // issued back-to-back, no mem dep
      }
      #pragma unroll
      for (int k = 0; k < 4; ++k) {
        a0 += bf2f((u16)v[k][0]) * w[k];
        a1 += bf2f((u16)v[k][1]) * w[k];
        a2 += bf2f((u16)v[k][2]) * w[k];
        a3 += bf2f((u16)v[k][3]) * w[k];
      }
    }
  }

  // fold edge-groups: lanes differing in bits 4,5 hold partials of the same dims
  a0 += __shfl_xor(a0, 16); a0 += __shfl_xor(a0, 32);
  a1 += __shfl_xor(a1, 16); a1 += __shfl_xor(a1, 32);
  a2 += __shfl_xor(a2, 16); a2 += __shfl_xor(a2, 32);
  a3 += __shfl_xor(a3, 16); a3 += __shfl_xor(a3, 32);
  if (g == 0) {
    s16x4 o;
    o[0] = (short)f2bf(fmaxf(a0 + bias[d0 + 0], 0.f));
    o[1] = (short)f2bf(fmaxf(a1 + bias[d0 + 1], 0.f));
    o[2] = (short)f2bf(fmaxf(a2 + bias[d0 + 2], 0.f));
    o[3] = (short)f2bf(fmaxf(a3 + bias[d0 + 3], 0.f));
    *(s16x4*)(out + (size_t)node * DD + d0) = o;
  }
}

// ---------------- launch ----------------

extern "C" void kernel_launch(void* const* d_in, const int* in_sizes, int n_in,
                              void* d_out, int out_size, void* d_ws, size_t ws_size,
                              hipStream_t stream) {
  const float* x    = (const float*)d_in[0];
  const int*   ei   = (const int*)d_in[1];
  const float* W1   = (const float*)d_in[2];
  const float* b1   = (const float*)d_in[3];
  const float* W2   = (const float*)d_in[4];
  const float* b2   = (const float*)d_in[5];
  const float* Wout = (const float*)d_in[6];
  const float* bout = (const float*)d_in[7];
  float* out = (float*)d_out;
  (void)in_sizes; (void)n_in; (void)out_size; (void)ws_size;

  char* ws = (char*)d_ws;
  size_t off = 0;
  auto alloc = [&](size_t bytes) -> char* {
    char* p = ws + off;
    off = (off + bytes + 255) & ~(size_t)255;
    return p;
  };
  u16*   xb   = (u16*)alloc((size_t)MP * DD * 2);   // activations bf16 (pad rows unused-garbage)
  u16*   H    = (u16*)alloc((size_t)NN * DD * 2);   // GEMM output bf16
  u16*   W1T  = (u16*)alloc(512 * 512 * 2);
  u16*   W2T  = (u16*)alloc(512 * 512 * 2);
  u16*   WoT  = (u16*)alloc(256 * 512 * 2);
  int*   cnt  = (int*)alloc(NN * 4);
  float* dinv = (float*)alloc(NN * 4);
  int*   rowp = (int*)alloc((NN + 1) * 4);
  int*   cur  = (int*)alloc(NN * 4);
  int2*  csr  = (int2*)alloc((size_t)(EE + NN) * 8);
  int*   bsum = (int*)alloc(NSCAN * 4);
  int*   boff = (int*)alloc(NSCAN * 4);

  const int* srcp = ei;        // edge_index[0]
  const int* dstp = ei + EE;   // edge_index[1]

  setup_k<<<2756, 256, 0, stream>>>(cnt, W1, W1T, W2, W2T, Wout, WoT);
  count_k<<<(EE + 255) / 256, 256, 0, stream>>>(dstp, cnt);
  scan1_k<<<NSCAN, 256, 0, stream>>>(cnt, bsum);
  scan2_k<<<1, 256, 0, stream>>>(bsum, boff);
  scan3_k<<<NSCAN, 256, 0, stream>>>(cnt, boff, rowp, cur, dinv);

  const int agg_grid = (NN / 4) * 8;            // 12500 node-groups x 8 XCD slices

  // layer 1 (fused scatter): H = bf16(x) @ W1 ; xb = relu(agg(H) + b1)
  gemm1_k<<<SCB + G1TILES, 256, 0, stream>>>(x, W1T, H, srcp, dstp, dinv, cur, csr);
  aggregate_k<<<agg_grid, 256, 0, stream>>>(H, rowp, csr, b1, xb);
  // layer 2
  gemm_k<1><<<(MP / 128) * (512 / 128), 256, 0, stream>>>(xb, W2T, (void*)H, nullptr, NN, 512);
  aggregate_k<<<agg_grid, 256, 0, stream>>>(H, rowp, csr, b2, xb);
  // output layer
  gemm_k<0><<<(MP / 128) * (256 / 128), 256, 0, stream>>>(xb, WoT, (void*)out, bout, NN, 256);
}

// Round 10
// 450.817 us; speedup vs baseline: 1.5352x; 1.1407x over previous
//
#include <hip/hip_runtime.h>

#define NN 50000
#define MP 50048   // 391 * 128
#define DD 512
#define EE 800000
#define NSCAN 196  // ceil(NN/256)
#define SCB 3321   // ceil((EE+NN)/256) scatter blocks fused into gemm1
#define G1TILES 1564  // (MP/128)*(512/128)

typedef unsigned short u16;
typedef __attribute__((ext_vector_type(4))) float f32x4;
typedef __attribute__((ext_vector_type(8))) __bf16 bf16x8;
typedef __attribute__((ext_vector_type(8))) short s16x8;
typedef __attribute__((ext_vector_type(4))) short s16x4;

typedef __attribute__((address_space(1))) const void GVoid;
typedef __attribute__((address_space(3))) void LVoid;

__device__ __forceinline__ u16 f2bf(float f) {
  union { float f; unsigned u; } x; x.f = f;
  unsigned r = x.u + 0x7fffu + ((x.u >> 16) & 1u);   // RTNE
  return (u16)(r >> 16);
}
__device__ __forceinline__ float bf2f(u16 b) {
  union { unsigned u; float f; } x; x.u = ((unsigned)b) << 16;
  return x.f;
}

// ---------------- setup: cnt=1, weight transposes, csr pad zero ----------------

__global__ __launch_bounds__(256) void setup_k(int* __restrict__ cnt,
                                               const float* __restrict__ W1, u16* __restrict__ W1T,
                                               const float* __restrict__ W2, u16* __restrict__ W2T,
                                               const float* __restrict__ Wo, u16* __restrict__ WoT,
                                               int2* __restrict__ csr) {
  const int b = (int)blockIdx.x, t = threadIdx.x;
  if (b < 196) {
    int i = b * 256 + t;
    if (i < NN) cnt[i] = 1;                    // self-loop pre-counted
    if (b == 0 && t < 64) csr[EE + NN + t] = make_int2(0, 0);   // prefetch-overshoot pad
    return;
  }
  const float* W; u16* WT; int ncols, idx;
  if (b < 1220)      { W = W1; WT = W1T; ncols = 512; idx = (b - 196) * 256 + t; }
  else if (b < 2244) { W = W2; WT = W2T; ncols = 512; idx = (b - 1220) * 256 + t; }
  else               { W = Wo; WT = WoT; ncols = 256; idx = (b - 2244) * 256 + t; }
  if (idx >= 512 * ncols) return;
  int n = idx >> 9, k = idx & 511;             // WT[ncols][512] = W^T
  WT[idx] = f2bf(W[(size_t)k * ncols + n]);
}

__global__ __launch_bounds__(256) void count_k(const int* __restrict__ dst, int* __restrict__ cnt) {
  int e = blockIdx.x * 256 + threadIdx.x;
  if (e < EE) atomicAdd(&cnt[dst[e]], 1);
}

// --- 3-stage parallel exclusive scan over cnt[NN]; scan3 also emits dinv ---

__global__ __launch_bounds__(256) void scan1_k(const int* __restrict__ cnt, int* __restrict__ bsum) {
  __shared__ int s[256];
  const int t = threadIdx.x;
  const int i = blockIdx.x * 256 + t;
  s[t] = (i < NN) ? cnt[i] : 0;
  __syncthreads();
  for (int off = 128; off > 0; off >>= 1) {
    if (t < off) s[t] += s[t + off];
    __syncthreads();
  }
  if (t == 0) bsum[blockIdx.x] = s[0];
}

__global__ __launch_bounds__(256) void scan2_k(const int* __restrict__ bsum, int* __restrict__ boff) {
  __shared__ int s[256];
  const int t = threadIdx.x;
  const int v = (t < NSCAN) ? bsum[t] : 0;
  s[t] = v;
  __syncthreads();
  for (int off = 1; off < 256; off <<= 1) {    // inclusive Hillis-Steele
    int a = s[t];
    int b = (t >= off) ? s[t - off] : 0;
    __syncthreads();
    s[t] = a + b;
    __syncthreads();
  }
  if (t < NSCAN) boff[t] = s[t] - v;           // exclusive
}

__global__ __launch_bounds__(256) void scan3_k(const int* __restrict__ cnt, const int* __restrict__ boff,
                                               int* __restrict__ rowp, int* __restrict__ cursor,
                                               float* __restrict__ dinv) {
  __shared__ int s[256];
  const int t = threadIdx.x;
  const int i = blockIdx.x * 256 + t;
  const int v = (i < NN) ? cnt[i] : 0;
  s[t] = v;
  __syncthreads();
  for (int off = 1; off < 256; off <<= 1) {    // inclusive
    int a = s[t];
    int b = (t >= off) ? s[t - off] : 0;
    __syncthreads();
    s[t] = a + b;
    __syncthreads();
  }
  const int excl = s[t] - v + boff[blockIdx.x];
  if (i < NN) {
    rowp[i] = excl; cursor[i] = excl;
    dinv[i] = rsqrtf((float)v);                // v includes self-loop
  }
  if (i == NN - 1) rowp[NN] = excl + v;        // total = EE + NN
}

// ---------------- GEMM-1 (f32 A direct, reg-staged) + fused scatter blocks ----------------

__global__ __launch_bounds__(256) void gemm1_k(const float* __restrict__ X, const u16* __restrict__ BT,
                                               u16* __restrict__ C,
                                               const int* __restrict__ src, const int* __restrict__ dst,
                                               const float* __restrict__ dinv, int* __restrict__ cursor,
                                               int2* __restrict__ csr) {
  __shared__ u16 As[2][128 * 32];
  __shared__ u16 Bs[2][128 * 32];
  const int t = threadIdx.x;

  if (blockIdx.x < SCB) {                      // ---- scatter branch ----
    int e = (int)blockIdx.x * 256 + t;
    if (e < EE) {
      int d = dst[e], sn = src[e];
      int pos = atomicAdd(&cursor[d], 1);
      csr[pos] = make_int2(sn, __float_as_int(dinv[sn] * dinv[d]));
    } else if (e < EE + NN) {
      int i = e - EE;                          // self-loop edge
      int pos = atomicAdd(&cursor[i], 1);
      float di = dinv[i];
      csr[pos] = make_int2(i, __float_as_int(di * di));
    }
    return;
  }

  // ---- GEMM branch: bijective XCD chunking over G1TILES ----
  const int g = (int)blockIdx.x - SCB;
  const int xcd = g & 7;
  const int idx = g >> 3;
  const int q = G1TILES >> 3, r = G1TILES & 7;
  const int tile = (xcd < r ? xcd * (q + 1) : r * (q + 1) + (xcd - r) * q) + idx;
  const int bm = tile >> 2;                    // ntn = 4
  const int bn = tile & 3;

  const int lane = t & 63;
  const int wc = (t >> 6) & 1;
  const int wr = (t >> 7) & 1;
  f32x4 acc[4][4] = {};
  const int r0 = t >> 2;                        // staging row 0..63
  const int kc = (t & 3) * 8;                   // staging k-col (elements)
  const int row1 = bm * 128 + 64 + r0;          // only the +64 region can exceed NN
  const float* Xp0 = X + (size_t)(bm * 128 + r0) * DD + kc;
  const float* Xp1 = X + (size_t)(row1 < NN ? row1 : NN - 1) * DD + kc;
  const u16* Bb = BT + (size_t)bn * 128 * DD + (size_t)r0 * DD + kc;

  f32x4 a0, a1, a2, a3;
  auto loadA = [&](int kt) {
    a0 = *(const f32x4*)(Xp0 + kt);
    a1 = *(const f32x4*)(Xp0 + kt + 4);
    a2 = *(const f32x4*)(Xp1 + kt);
    a3 = *(const f32x4*)(Xp1 + kt + 4);
  };
  auto writeA = [&](int buf) {
    bf16x8 w0, w1;
    #pragma unroll
    for (int j = 0; j < 4; ++j) {
      w0[j] = (__bf16)a0[j]; w0[4 + j] = (__bf16)a1[j];
      w1[j] = (__bf16)a2[j]; w1[4 + j] = (__bf16)a3[j];
    }
    *(bf16x8*)&As[buf][t * 8] = w0;
    *(bf16x8*)&As[buf][2048 + t * 8] = w1;
  };
  auto stageB = [&](int buf, int kt) {
    __builtin_amdgcn_global_load_lds((GVoid*)(Bb + kt),           (LVoid*)(&Bs[buf][t * 8]),        16, 0, 0);
    __builtin_amdgcn_global_load_lds((GVoid*)(Bb + 64 * DD + kt), (LVoid*)(&Bs[buf][2048 + t * 8]), 16, 0, 0);
  };

  loadA(0);
  stageB(0, 0);
  writeA(0);
  __syncthreads();                              // buf0 ready (A written, B drained)

  #pragma unroll 2
  for (int step = 0; step < 16; ++step) {
    const int cur = step & 1;
    if (step < 15) { loadA((step + 1) * 32); stageB(cur ^ 1, (step + 1) * 32); }
    bf16x8 af[4], bv[4];
    #pragma unroll
    for (int m = 0; m < 4; ++m)
      af[m] = *(const bf16x8*)&As[cur][(wr * 64 + m * 16 + (lane & 15)) * 32 + (lane >> 4) * 8];
    #pragma unroll
    for (int n = 0; n < 4; ++n)
      bv[n] = *(const bf16x8*)&Bs[cur][(wc * 64 + n * 16 + (lane & 15)) * 32 + (lane >> 4) * 8];
    #pragma unroll
    for (int m = 0; m < 4; ++m) {
      #pragma unroll
      for (int n = 0; n < 4; ++n)
        acc[m][n] = __builtin_amdgcn_mfma_f32_16x16x32_bf16(af[m], bv[n], acc[m][n], 0, 0, 0);
    }
    if (step < 15) writeA(cur ^ 1);             // cvt + ds_write after MFMA (loads in flight during MFMA)
    __syncthreads();
  }

  const int rb = bm * 128 + wr * 64 + ((lane >> 4) * 4);
  const int cb = bn * 128 + wc * 64 + (lane & 15);
  #pragma unroll
  for (int m = 0; m < 4; ++m) {
    #pragma unroll
    for (int rr = 0; rr < 4; ++rr) {
      const int row = rb + m * 16 + rr;
      if (row < NN) {
        #pragma unroll
        for (int n = 0; n < 4; ++n)
          C[(size_t)row * 512 + cb + n * 16] = f2bf(acc[m][n][rr]);
      }
    }
  }
}

// ---------------- bf16 MFMA GEMM: m97 structure + 2-phase double buffer (layers 2,3) ----------------

template<int OUT_BF16>
__global__ __launch_bounds__(256) void gemm_k(const u16* __restrict__ A, const u16* __restrict__ BT,
                                              void* __restrict__ Cv, const float* __restrict__ bias,
                                              int M, int N) {
  const int nwg = (int)gridDim.x;
  const int id = (int)blockIdx.x;
  const int xcd = id & 7;
  const int idx = id >> 3;
  const int q = nwg >> 3, r = nwg & 7;
  const int tile = (xcd < r ? xcd * (q + 1) : r * (q + 1) + (xcd - r) * q) + idx;
  const int ntn = N >> 7;
  const int bm = tile / ntn;
  const int bn = tile % ntn;

  __shared__ u16 As[2][128 * 32];
  __shared__ u16 Bs[2][128 * 32];
  const int t = threadIdx.x;
  const int lane = t & 63;
  const int wc = (t >> 6) & 1;
  const int wr = (t >> 7) & 1;
  f32x4 acc[4][4] = {};
  const int r0 = t >> 2;
  const int kc = (t & 3) * 8;
  const u16* Ab = A + (size_t)bm * 128 * DD + (size_t)r0 * DD + kc;
  const u16* Bb = BT + (size_t)bn * 128 * DD + (size_t)r0 * DD + kc;

  auto stage = [&](int buf, int kt) {
    __builtin_amdgcn_global_load_lds((GVoid*)(Ab + kt),           (LVoid*)(&As[buf][t * 8]),        16, 0, 0);
    __builtin_amdgcn_global_load_lds((GVoid*)(Ab + 64 * DD + kt), (LVoid*)(&As[buf][2048 + t * 8]), 16, 0, 0);
    __builtin_amdgcn_global_load_lds((GVoid*)(Bb + kt),           (LVoid*)(&Bs[buf][t * 8]),        16, 0, 0);
    __builtin_amdgcn_global_load_lds((GVoid*)(Bb + 64 * DD + kt), (LVoid*)(&Bs[buf][2048 + t * 8]), 16, 0, 0);
  };

  stage(0, 0);
  __syncthreads();

  #pragma unroll 2
  for (int step = 0; step < 16; ++step) {
    const int cur = step & 1;
    if (step < 15) stage(cur ^ 1, (step + 1) * 32);
    bf16x8 af[4], bv[4];
    #pragma unroll
    for (int m = 0; m < 4; ++m)
      af[m] = *(const bf16x8*)&As[cur][(wr * 64 + m * 16 + (lane & 15)) * 32 + (lane >> 4) * 8];
    #pragma unroll
    for (int n = 0; n < 4; ++n)
      bv[n] = *(const bf16x8*)&Bs[cur][(wc * 64 + n * 16 + (lane & 15)) * 32 + (lane >> 4) * 8];
    #pragma unroll
    for (int m = 0; m < 4; ++m) {
      #pragma unroll
      for (int n = 0; n < 4; ++n)
        acc[m][n] = __builtin_amdgcn_mfma_f32_16x16x32_bf16(af[m], bv[n], acc[m][n], 0, 0, 0);
    }
    __syncthreads();
  }

  const int rb = bm * 128 + wr * 64 + ((lane >> 4) * 4);
  const int cb = bn * 128 + wc * 64 + (lane & 15);
  #pragma unroll
  for (int m = 0; m < 4; ++m) {
    #pragma unroll
    for (int rr = 0; rr < 4; ++rr) {
      const int row = rb + m * 16 + rr;
      if (row < M) {
        #pragma unroll
        for (int n = 0; n < 4; ++n) {
          const int col = cb + n * 16;
          float v = acc[m][n][rr];
          if (bias) v += bias[col];
          if (OUT_BF16) ((u16*)Cv)[(size_t)row * N + col] = f2bf(v);
          else          ((float*)Cv)[(size_t)row * N + col] = v;
        }
      }
    }
  }
}

// ---------------- CSR aggregation: XCD-pinned 64-dim slices, 4 nodes/wave, no shfl ----------------

__global__ __launch_bounds__(256) void aggregate_k(const u16* __restrict__ H, const int* __restrict__ rowp,
                                                   const int2* __restrict__ csr,
                                                   const float* __restrict__ bias,
                                                   u16* __restrict__ out) {
  const int slice = (int)blockIdx.x & 7;        // XCD-pinned dim slice
  const int grp = (int)blockIdx.x >> 3;         // node group 0..3124
  const int wid = threadIdx.x >> 6;
  const int lane = threadIdx.x & 63;
  const int g = lane >> 4;                      // node sub-group 0..3
  const int l = lane & 15;                      // dim sub-lane
  const int node = grp * 16 + wid * 4 + g;      // NN = 16 * 3125 exactly
  const int d0 = slice * 64 + l * 4;
  const int beg = rowp[node];
  const int dg = rowp[node + 1] - beg;
  const int rounds = (dg + 3) >> 2;
  const u16* Hd = H + d0;
  float a0 = 0.f, a1 = 0.f, a2 = 0.f, a3 = 0.f;

  int2 e0 = csr[beg], e1 = csr[beg + 1], e2 = csr[beg + 2], e3 = csr[beg + 3];
  for (int b = 0; b < rounds; ++b) {
    const int r = b * 4;
    // issue 4 independent gathers (2KB/wave in flight)
    const s16x4 v0 = *(const s16x4*)(Hd + (size_t)e0.x * DD);
    const s16x4 v1 = *(const s16x4*)(Hd + (size_t)e1.x * DD);
    const s16x4 v2 = *(const s16x4*)(Hd + (size_t)e2.x * DD);
    const s16x4 v3 = *(const s16x4*)(Hd + (size_t)e3.x * DD);
    // prefetch next block's entries (uniform within group, 8B aligned)
    const int nb = beg + r + 4;
    const int2 f0 = csr[nb], f1 = csr[nb + 1], f2 = csr[nb + 2], f3 = csr[nb + 3];
    const float w0 = (r + 0 < dg) ? __int_as_float(e0.y) : 0.f;
    const float w1 = (r + 1 < dg) ? __int_as_float(e1.y) : 0.f;
    const float w2 = (r + 2 < dg) ? __int_as_float(e2.y) : 0.f;
    const float w3 = (r + 3 < dg) ? __int_as_float(e3.y) : 0.f;
    a0 += bf2f((u16)v0[0]) * w0 + bf2f((u16)v1[0]) * w1 + bf2f((u16)v2[0]) * w2 + bf2f((u16)v3[0]) * w3;
    a1 += bf2f((u16)v0[1]) * w0 + bf2f((u16)v1[1]) * w1 + bf2f((u16)v2[1]) * w2 + bf2f((u16)v3[1]) * w3;
    a2 += bf2f((u16)v0[2]) * w0 + bf2f((u16)v1[2]) * w1 + bf2f((u16)v2[2]) * w2 + bf2f((u16)v3[2]) * w3;
    a3 += bf2f((u16)v0[3]) * w0 + bf2f((u16)v1[3]) * w1 + bf2f((u16)v2[3]) * w2 + bf2f((u16)v3[3]) * w3;
    e0 = f0; e1 = f1; e2 = f2; e3 = f3;
  }

  s16x4 o;
  o[0] = (short)f2bf(fmaxf(a0 + bias[d0 + 0], 0.f));
  o[1] = (short)f2bf(fmaxf(a1 + bias[d0 + 1], 0.f));
  o[2] = (short)f2bf(fmaxf(a2 + bias[d0 + 2], 0.f));
  o[3] = (short)f2bf(fmaxf(a3 + bias[d0 + 3], 0.f));
  *(s16x4*)(out + (size_t)node * DD + d0) = o;
}

// ---------------- launch ----------------

extern "C" void kernel_launch(void* const* d_in, const int* in_sizes, int n_in,
                              void* d_out, int out_size, void* d_ws, size_t ws_size,
                              hipStream_t stream) {
  const float* x    = (const float*)d_in[0];
  const int*   ei   = (const int*)d_in[1];
  const float* W1   = (const float*)d_in[2];
  const float* b1   = (const float*)d_in[3];
  const float* W2   = (const float*)d_in[4];
  const float* b2   = (const float*)d_in[5];
  const float* Wout = (const float*)d_in[6];
  const float* bout = (const float*)d_in[7];
  float* out = (float*)d_out;
  (void)in_sizes; (void)n_in; (void)out_size; (void)ws_size;

  char* ws = (char*)d_ws;
  size_t off = 0;
  auto alloc = [&](size_t bytes) -> char* {
    char* p = ws + off;
    off = (off + bytes + 255) & ~(size_t)255;
    return p;
  };
  u16*   xb   = (u16*)alloc((size_t)MP * DD * 2);   // activations bf16 (pad rows unused-garbage)
  u16*   H    = (u16*)alloc((size_t)NN * DD * 2);   // GEMM output bf16
  u16*   W1T  = (u16*)alloc(512 * 512 * 2);
  u16*   W2T  = (u16*)alloc(512 * 512 * 2);
  u16*   WoT  = (u16*)alloc(256 * 512 * 2);
  int*   cnt  = (int*)alloc(NN * 4);
  float* dinv = (float*)alloc(NN * 4);
  int*   rowp = (int*)alloc((NN + 1) * 4);
  int*   cur  = (int*)alloc(NN * 4);
  int2*  csr  = (int2*)alloc((size_t)(EE + NN + 64) * 8);   // +64 zeroed pad
  int*   bsum = (int*)alloc(NSCAN * 4);
  int*   boff = (int*)alloc(NSCAN * 4);

  const int* srcp = ei;        // edge_index[0]
  const int* dstp = ei + EE;   // edge_index[1]

  setup_k<<<2756, 256, 0, stream>>>(cnt, W1, W1T, W2, W2T, Wout, WoT, csr);
  count_k<<<(EE + 255) / 256, 256, 0, stream>>>(dstp, cnt);
  scan1_k<<<NSCAN, 256, 0, stream>>>(cnt, bsum);
  scan2_k<<<1, 256, 0, stream>>>(bsum, boff);
  scan3_k<<<NSCAN, 256, 0, stream>>>(cnt, boff, rowp, cur, dinv);

  const int agg_grid = (NN / 16) * 8;           // 3125 node-groups x 8 XCD slices

  // layer 1 (fused scatter): H = bf16(x) @ W1 ; xb = relu(agg(H) + b1)
  gemm1_k<<<SCB + G1TILES, 256, 0, stream>>>(x, W1T, H, srcp, dstp, dinv, cur, csr);
  aggregate_k<<<agg_grid, 256, 0, stream>>>(H, rowp, csr, b1, xb);
  // layer 2
  gemm_k<1><<<(MP / 128) * (512 / 128), 256, 0, stream>>>(xb, W2T, (void*)H, nullptr, NN, 512);
  aggregate_k<<<agg_grid, 256, 0, stream>>>(H, rowp, csr, b2, xb);
  // output layer
  gemm_k<0><<<(MP / 128) * (256 / 128), 256, 0, stream>>>(xb, WoT, (void*)out, bout, NN, 256);
}